// Round 1
// baseline (9.646 us; speedup 1.0000x reference)
//
#include <hip/hip_runtime.h>
#include <hip/hip_bf16.h>

// out[k] = || X[ids[2k], :] - X[ids[2k+1], :] ||_2  for k in [0, n_pairs)
// X: [n, d] f32 row-major; ids: [2*n_pairs] int32; out: [n_pairs] f32.
// One 64-lane wave per pair; d assumed divisible by 4 (d=512 here).
__global__ void rips_pairs_kernel(const float* __restrict__ X,
                                  const int* __restrict__ ids,
                                  float* __restrict__ out,
                                  int d) {
    const int p    = blockIdx.x;      // pair index
    const int lane = threadIdx.x;     // 0..63

    const int r = ids[2 * p];
    const int c = ids[2 * p + 1];

    const float4* __restrict__ xr =
        reinterpret_cast<const float4*>(X + (size_t)r * (size_t)d);
    const float4* __restrict__ xc =
        reinterpret_cast<const float4*>(X + (size_t)c * (size_t)d);

    const int nvec = d >> 2;          // float4 count per row (128 for d=512)

    float acc = 0.0f;
    for (int i = lane; i < nvec; i += 64) {
        float4 a = xr[i];
        float4 b = xc[i];
        float dx = a.x - b.x;
        float dy = a.y - b.y;
        float dz = a.z - b.z;
        float dw = a.w - b.w;
        acc = fmaf(dx, dx, acc);
        acc = fmaf(dy, dy, acc);
        acc = fmaf(dz, dz, acc);
        acc = fmaf(dw, dw, acc);
    }

    // 64-lane wave reduction (wavefront = 64 on CDNA)
    #pragma unroll
    for (int off = 32; off > 0; off >>= 1) {
        acc += __shfl_down(acc, off, 64);
    }

    if (lane == 0) {
        out[p] = sqrtf(acc);
    }
}

extern "C" void kernel_launch(void* const* d_in, const int* in_sizes, int n_in,
                              void* d_out, int out_size, void* d_ws, size_t ws_size,
                              hipStream_t stream) {
    const float* X   = (const float*)d_in[0];   // [n, d] f32
    const int*   ids = (const int*)d_in[1];     // [4*CARD] int32

    float* out = (float*)d_out;                 // [CARD, 2] f32 flat = n_pairs floats

    const int n_pairs = in_sizes[1] / 2;        // 100
    const int d       = 512;                    // per reference setup (n=4096, d=512)

    rips_pairs_kernel<<<n_pairs, 64, 0, stream>>>(X, ids, out, d);
}